// Round 12
// baseline (225.721 us; speedup 1.0000x reference)
//
#include <hip/hip_runtime.h>
#include <hip/hip_bf16.h>

typedef __bf16 bf16x8 __attribute__((ext_vector_type(8)));
typedef float  f32x4  __attribute__((ext_vector_type(4)));

#define N_NODES 10000
#define N_EDGES 320000

// workspace byte offsets (16B aligned)
#define WS_TEMB   0u         // 128*256*4
#define WS_H      131072u    // 10000*256*2 bf16
#define WS_W1AT   5251072u   // atom W1^T [256][256] bf16
#define WS_W2AT   5382144u   // atom W2^T [112][256] bf16
#define WS_W1BT   5439488u   // bond W1^T [256][512] bf16
#define WS_W2BT   5701632u   // bond W2^T [16][256] bf16

// ---------------- prep: 4 weight transposes + timestep embedding ----------------
__global__ void prep_kernel(const float* __restrict__ aw1, const float* __restrict__ aw2,
                            const float* __restrict__ bw1, const float* __restrict__ bw2,
                            const float* __restrict__ t,
                            __hip_bfloat16* __restrict__ W1a, __hip_bfloat16* __restrict__ W2a,
                            __hip_bfloat16* __restrict__ W1b, __hip_bfloat16* __restrict__ W2b,
                            float* __restrict__ temb)
{
    int blk = blockIdx.x;
    if (blk < 256) {                       // atom w1 -> [256 n][256 k]
        int i = blk * 256 + threadIdx.x;
        int n = i >> 8, k = i & 255;
        W1a[i] = __float2bfloat16(aw1[k * 256 + n]);
    } else if (blk < 368) {                // atom w2 [256][100] -> [112 n][256 k]
        int i = (blk - 256) * 256 + threadIdx.x;
        int n = i >> 8, k = i & 255;
        W2a[i] = __float2bfloat16(n < 100 ? aw2[k * 100 + n] : 0.0f);
    } else if (blk < 880) {                // bond w1 [512][256] -> [256 n][512 k]
        int i = (blk - 368) * 256 + threadIdx.x;
        int n = i >> 9, k = i & 511;
        W1b[i] = __float2bfloat16(bw1[k * 256 + n]);
    } else if (blk < 896) {                // bond w2 [256][5] -> [16 n][256 k]
        int i = (blk - 880) * 256 + threadIdx.x;
        int n = i >> 8, k = i & 255;
        W2b[i] = __float2bfloat16(n < 5 ? bw2[k * 5 + n] : 0.0f);
    } else {                               // temb: blocks 896..959
        int q = blk - 896;
        int b = q * 2 + (threadIdx.x >> 7);
        int i = threadIdx.x & 127;
        float freq = expf((float)i * (-9.210340371976184f / 127.0f));
        float ang  = t[b] * freq;
        temb[b * 256 + i]       = sinf(ang);
        temb[b * 256 + 128 + i] = cosf(ang);
    }
}

// ---------------- h = bf16(nf + temb[batch]) + nf copy + pos copy ----------------
__global__ void h_kernel(const float* __restrict__ nf, const int* __restrict__ batch,
                         const float* __restrict__ temb, __hip_bfloat16* __restrict__ hb,
                         float* __restrict__ out_nf,
                         const float4* __restrict__ pos_src, float4* __restrict__ pos_dst)
{
    int blk = blockIdx.x;
    if (blk >= 1250) {                     // pos copy: 30000 floats
        int j = (blk - 1250) * 256 + threadIdx.x;
        if (j < 7500) pos_dst[j] = pos_src[j];
        return;
    }
    int i = blk * 256 + threadIdx.x;       // one thread per 8 elems
    int n = i >> 5;
    int c = (i & 31) << 3;
    const float4* p = (const float4*)(nf + (size_t)n * 256 + c);
    float4 v0 = p[0], v1 = p[1];
    int b = batch[n];
    const float4* q = (const float4*)(temb + (size_t)b * 256 + c);
    float4 t0 = q[0], t1 = q[1];
    union { int4 i4; __hip_bfloat16 h[8]; } u;
    u.h[0] = __float2bfloat16(v0.x + t0.x);
    u.h[1] = __float2bfloat16(v0.y + t0.y);
    u.h[2] = __float2bfloat16(v0.z + t0.z);
    u.h[3] = __float2bfloat16(v0.w + t0.w);
    u.h[4] = __float2bfloat16(v1.x + t1.x);
    u.h[5] = __float2bfloat16(v1.y + t1.y);
    u.h[6] = __float2bfloat16(v1.z + t1.z);
    u.h[7] = __float2bfloat16(v1.w + t1.w);
    *(int4*)((char*)hb + (size_t)n * 512 + (size_t)c * 2) = u.i4;
    float4* o = (float4*)(out_nf + (size_t)n * 256 + c);
    o[0] = v0; o[1] = v1;
}

// ---------------- async global->LDS 16B ----------------
__device__ __forceinline__ void gload16(const void* g, void* l)
{
    __builtin_amdgcn_global_load_lds(
        (const __attribute__((address_space(1))) unsigned int*)g,
        (__attribute__((address_space(3))) unsigned int*)l, 16, 0, 0);
}

#define WAIT_V4    asm volatile("s_waitcnt vmcnt(4)" ::: "memory")
#define WAIT_V0    asm volatile("s_waitcnt vmcnt(0)" ::: "memory")
#define WAIT_LGKM0 asm volatile("s_waitcnt lgkmcnt(0)" ::: "memory")
#define SCHEDB     __builtin_amdgcn_sched_barrier(0)
#define BARRIER    __builtin_amdgcn_s_barrier()

// ---------------- fused 2-layer MLP, 256^2 tile, 4-phase/K-tile counted-vmcnt pipeline ----
// Geometry: BM=BN=256, BK=64, NT=K/64 tiles; 512 thr = 8 waves (2M x 4N); wave(wm,wn) owns
// rows [wm*128,+128) x cols [wn*64,+64) -> acc[8][4].
// LDS 128KB: buf[b] (b=kt&1) at b*64KB; in buf: A-k0 @0, A-k1 @16K, B-k0 @32K, B-k1 @48K;
// each half = [256 rows][64B], slot swizzle slot(j,r) = ((j^(r&3)) + ((r>>2)&3))&3 (2-way
// bank alias = free); inverse applied on the global SOURCE (gload dest stays linear, #21).
// Per K-tile, 4 phases; phase p: {ds_read frags || issue one half-stage (2 gloads) for
// tile kt+1} -> barrier -> lgkmcnt(0) -> setprio(1) -> 16 MFMA -> setprio(0) -> barrier.
// Counted vmcnt(4) at ends of ph1 & ph3: retires exactly the 2 halves (4 loads/wave,
// issued ~1 tile earlier) needed by the next 2 phases; loads never drain to 0 in-loop.
// Phase->data: ph0/ph1 use k0 halves (mi 0-3 / 4-7), ph2/ph3 use k1 halves.
template<int NT, bool GATHER, int N2F, int N2REAL>
__global__ __launch_bounds__(512, 2) void mlp_kernel(
    const __hip_bfloat16* __restrict__ hb,    // [N_NODES][256] bf16
    const __hip_bfloat16* __restrict__ w1t,   // [256 n][NT*64 k] bf16
    const __hip_bfloat16* __restrict__ w2t,   // [N2F*16 n][256 k] bf16
    const float* __restrict__ b1,             // [256]
    const float* __restrict__ b2,             // [N2REAL]
    const int*  __restrict__ eidx,            // GATHER: [2][N_EDGES]
    int M,
    float* __restrict__ out)                  // [M][N2REAL]
{
    extern __shared__ char lds[];
    const int t   = threadIdx.x;
    const int wid = t >> 6;                 // 0..7
    const int l   = t & 63;
    const int wm  = wid >> 2;               // 0..1
    const int wn  = wid & 3;                // 0..3
    const int m0  = blockIdx.x * 256;

    // stage-source swizzle (lane-const): dest slot s=t&3, row r: (r>>2)&3=(t>>4)&3,
    // r&3=(t>>2)&3  ->  logical chunk j = ((s-((t>>4)&3))&3) ^ ((t>>2)&3)
    const int jsw = (((((t & 3) - ((t >> 4) & 3)) & 3) ^ ((t >> 2) & 3)) << 4);
    // frag-read slot (lane-const): j=l>>4, r&3=l&3, (r>>2)&3=(l>>2)&3
    const int slotF = (((((l >> 4) ^ (l & 3)) + ((l >> 2) & 3)) & 3) << 4);

    // sources: instr i (0,1) covers rows i*128 + (t>>2)
    const char* hbase  = (const char*)hb;
    const char* w1base = (const char*)w1t;
    long srcA[2][2], srcB[2];
    #pragma unroll
    for (int i = 0; i < 2; ++i) {
        int r = i * 128 + (t >> 2);
        if (GATHER) {
            int e = m0 + r;
            srcA[i][0] = (long)eidx[e] * 512 + jsw;
            srcA[i][1] = (long)eidx[N_EDGES + e] * 512 + jsw;
        } else {
            int rr = m0 + r; if (rr > M - 1) rr = M - 1;
            srcA[i][0] = srcA[i][1] = (long)rr * 512 + jsw;
        }
        srcB[i] = (long)(i * 128 + (t >> 2)) * (NT * 128) + jsw;
    }

    auto stageA = [&](int ks, int k1) {
        char* d = lds + ((ks & 1) << 16) + k1 * 16384 + wid * 1024;
        int side = (GATHER && ks >= NT / 2) ? 1 : 0;
        int koff = (GATHER ? (ks & (NT / 2 - 1)) : ks) * 128 + k1 * 64;
        gload16(hbase + srcA[0][side] + koff, d);
        gload16(hbase + srcA[1][side] + koff, d + 8192);
    };
    auto stageB = [&](int ks, int k1) {
        char* d = lds + ((ks & 1) << 16) + 32768 + k1 * 16384 + wid * 1024;
        long koff = (long)ks * 128 + k1 * 64;
        gload16(w1base + srcB[0] + koff, d);
        gload16(w1base + srcB[1] + koff, d + 8192);
    };

    f32x4 acc[8][4];
    #pragma unroll
    for (int i = 0; i < 8; ++i)
        #pragma unroll
        for (int j = 0; j < 4; ++j) acc[i][j] = f32x4{0.f, 0.f, 0.f, 0.f};

    bf16x8 af[4], bfr[4];
    auto LOAD_AF = [&](const char* base, int k1, int mig) {
        #pragma unroll
        for (int a = 0; a < 4; ++a) {
            int R = wm * 128 + (mig * 4 + a) * 16 + (l & 15);
            af[a] = *(const bf16x8*)(base + k1 * 16384 + R * 64 + slotF);
        }
    };
    auto LOAD_BFR = [&](const char* base, int k1) {
        #pragma unroll
        for (int ni = 0; ni < 4; ++ni) {
            int R = wn * 64 + ni * 16 + (l & 15);
            bfr[ni] = *(const bf16x8*)(base + 32768 + k1 * 16384 + R * 64 + slotF);
        }
    };
    auto MFMA16 = [&](int mig) {
        __builtin_amdgcn_s_setprio(1);
        #pragma unroll
        for (int a = 0; a < 4; ++a)
            #pragma unroll
            for (int ni = 0; ni < 4; ++ni)
                acc[mig * 4 + a][ni] =
                    __builtin_amdgcn_mfma_f32_16x16x32_bf16(af[a], bfr[ni], acc[mig * 4 + a][ni], 0, 0, 0);
        __builtin_amdgcn_s_setprio(0);
    };

    // prologue: stage tile 0 fully; k0 halves must land before ph0
    stageA(0, 0); stageB(0, 0); stageA(0, 1); stageB(0, 1);
    WAIT_V4; BARRIER; SCHEDB;

    for (int kt = 0; kt < NT; ++kt) {
        const char* cur = lds + ((kt & 1) << 16);
        const bool pf = (kt + 1 < NT);
        // ---- phase 0: k0, mi 0-3 ----
        LOAD_AF(cur, 0, 0); LOAD_BFR(cur, 0);
        if (pf) stageA(kt + 1, 0);
        BARRIER; WAIT_LGKM0; SCHEDB;
        MFMA16(0);
        BARRIER;
        // ---- phase 1: k0, mi 4-7 ----
        LOAD_AF(cur, 0, 1);
        if (pf) stageB(kt + 1, 0);
        if (pf) { WAIT_V4; } else { WAIT_V0; }   // k1 halves of THIS tile now resident
        BARRIER; WAIT_LGKM0; SCHEDB;
        MFMA16(1);
        BARRIER;
        // ---- phase 2: k1, mi 0-3 ----
        LOAD_AF(cur, 1, 0); LOAD_BFR(cur, 1);
        if (pf) stageA(kt + 1, 1);
        BARRIER; WAIT_LGKM0; SCHEDB;
        MFMA16(0);
        BARRIER;
        // ---- phase 3: k1, mi 4-7 ----
        LOAD_AF(cur, 1, 1);
        if (pf) { stageB(kt + 1, 1); WAIT_V4; }  // k0 halves of NEXT tile resident
        BARRIER; WAIT_LGKM0; SCHEDB;
        MFMA16(1);
        BARRIER;
    }

    // ---- epilogue 1: hidden = relu(acc + b1) -> bf16 LDS [256 r][512B], XOR-swizzled ----
    __syncthreads();       // full drain; LDS re-purposed as Hid
    {
        float b1v[4];
        #pragma unroll
        for (int ni = 0; ni < 4; ++ni) b1v[ni] = b1[wn * 64 + ni * 16 + (l & 15)];
        #pragma unroll
        for (int mi = 0; mi < 8; ++mi)
            #pragma unroll
            for (int ni = 0; ni < 4; ++ni)
                #pragma unroll
                for (int r = 0; r < 4; ++r) {
                    int m = wm * 128 + mi * 16 + (l >> 4) * 4 + r;   // D row (m89 layout)
                    int n = wn * 64 + ni * 16 + (l & 15);            // D col
                    float v = fmaxf(acc[mi][ni][r] + b1v[ni], 0.0f);
                    int byte = m * 512 + ((((n >> 3) ^ (m & 7)) << 4)) + ((n & 7) << 1);
                    *(__hip_bfloat16*)(lds + byte) = __float2bfloat16(v);
                }
    }
    __syncthreads();

    // ---- layer 2: wave owns out rows [wid*32,+32); K=256 (8 k-steps); B from global ----
    f32x4 acc2[2][N2F];
    #pragma unroll
    for (int i = 0; i < 2; ++i)
        #pragma unroll
        for (int j = 0; j < N2F; ++j) acc2[i][j] = f32x4{0.f, 0.f, 0.f, 0.f};
    const char* w2base = (const char*)w2t;
    #pragma unroll
    for (int ks = 0; ks < 8; ++ks) {
        const int jx2 = (ks * 4 + (l >> 4)) ^ (l & 7);
        bf16x8 a2[2];
        #pragma unroll
        for (int mi2 = 0; mi2 < 2; ++mi2) {
            int r2 = wid * 32 + mi2 * 16 + (l & 15);
            a2[mi2] = *(const bf16x8*)(lds + r2 * 512 + (jx2 << 4));
        }
        #pragma unroll
        for (int nf2 = 0; nf2 < N2F; ++nf2) {
            bf16x8 b2f = *(const bf16x8*)(w2base + (nf2 * 16 + (l & 15)) * 512 + ks * 64 + (l >> 4) * 16);
            #pragma unroll
            for (int mi2 = 0; mi2 < 2; ++mi2)
                acc2[mi2][nf2] = __builtin_amdgcn_mfma_f32_16x16x32_bf16(a2[mi2], b2f, acc2[mi2][nf2], 0, 0, 0);
        }
    }
    #pragma unroll
    for (int nf2 = 0; nf2 < N2F; ++nf2) {
        int n = nf2 * 16 + (l & 15);
        if (n < N2REAL) {
            float b2v = b2[n];
            #pragma unroll
            for (int mi2 = 0; mi2 < 2; ++mi2)
                #pragma unroll
                for (int r = 0; r < 4; ++r) {
                    int gm = m0 + wid * 32 + mi2 * 16 + (l >> 4) * 4 + r;
                    if (gm < M)
                        out[(long)gm * N2REAL + n] = acc2[mi2][nf2][r] + b2v;
                }
        }
    }
}

// ---------------- launch ----------------
extern "C" void kernel_launch(void* const* d_in, const int* in_sizes, int n_in,
                              void* d_out, int out_size, void* d_ws, size_t ws_size,
                              hipStream_t stream)
{
    const float* node_features = (const float*)d_in[0];
    const float* pos_pred      = (const float*)d_in[1];
    const int*   edge_index    = (const int*)d_in[2];
    const int*   batch         = (const int*)d_in[3];
    const float* t_disc        = (const float*)d_in[4];
    const float* atom_w1       = (const float*)d_in[5];
    const float* atom_b1       = (const float*)d_in[6];
    const float* atom_w2       = (const float*)d_in[7];
    const float* atom_b2       = (const float*)d_in[8];
    const float* bond_w1       = (const float*)d_in[9];
    const float* bond_b1       = (const float*)d_in[10];
    const float* bond_w2       = (const float*)d_in[11];
    const float* bond_b2       = (const float*)d_in[12];

    char* ws = (char*)d_ws;
    float*          temb = (float*)(ws + WS_TEMB);
    __hip_bfloat16* hbf  = (__hip_bfloat16*)(ws + WS_H);
    __hip_bfloat16* W1at = (__hip_bfloat16*)(ws + WS_W1AT);
    __hip_bfloat16* W2at = (__hip_bfloat16*)(ws + WS_W2AT);
    __hip_bfloat16* W1bt = (__hip_bfloat16*)(ws + WS_W1BT);
    __hip_bfloat16* W2bt = (__hip_bfloat16*)(ws + WS_W2BT);

    float* out      = (float*)d_out;
    float* out_pos  = out;                 // 10000*3
    float* out_atom = out + 30000;         // 10000*100
    float* out_bond = out + 1030000;       // 320000*5
    float* out_nf   = out + 2630000;       // 10000*256

    prep_kernel<<<960, 256, 0, stream>>>(atom_w1, atom_w2, bond_w1, bond_w2, t_disc,
                                         W1at, W2at, W1bt, W2bt, temb);
    h_kernel<<<1280, 256, 0, stream>>>(node_features, batch, temb, hbf, out_nf,
                                       (const float4*)pos_pred, (float4*)out_pos);
    // atom MLP: M=10000, K=256 (NT=4), out 100 (pad 112)
    mlp_kernel<4, false, 7, 100><<<40, 512, 131072, stream>>>(
        hbf, W1at, W2at, atom_b1, atom_b2, nullptr, N_NODES, out_atom);
    // bond MLP: M=320000, K=512 (NT=8, gathered h[row];h[col]), out 5 (pad 16)
    mlp_kernel<8, true, 1, 5><<<1250, 512, 131072, stream>>>(
        hbf, W1bt, W2bt, bond_b1, bond_b2, edge_index, N_EDGES, out_bond);
}